// Round 10
// baseline (222.705 us; speedup 1.0000x reference)
//
#include <hip/hip_runtime.h>
#include <math.h>

#define NB 4
#define DD 128
#define HH 128
#define WW 128
#define VOX (DD*HH*WW)          // 2097152 = 2^21
#define NVOX (NB*VOX)           // 8388608

struct GaussW { float w[7]; };

__device__ __forceinline__ float4 f4zero() { float4 z; z.x = z.y = z.z = z.w = 0.f; return z; }

// ---------------------------------------------------------------------------
// |curl| of one float4 at (z, y, x0). Matches _fdiff (dup-last forward diff).
__device__ __forceinline__ float4 curl4_at(const float* __restrict__ u,
                                           const float* __restrict__ vv,
                                           const float* __restrict__ w,
                                           int z, int y, int x0) {
    int xq = x0 >> 2;
    size_t s = ((size_t)z << 14) | ((size_t)y << 7) | (size_t)x0;
    int dy = (y < 127) ? 128 : -128;
    int dz = (z < 127) ? 16384 : -16384;
    float sy = (y < 127) ? 1.f : -1.f;
    float sz = (z < 127) ? 1.f : -1.f;
    int dxp = (xq < 31) ? 4 : 0;

    const float4 wc  = *(const float4*)(w  + s);
    const float4 wyn = *(const float4*)(w  + s + dy);
    const float4 vc  = *(const float4*)(vv + s);
    const float4 vzn = *(const float4*)(vv + s + dz);
    const float4 uc  = *(const float4*)(u  + s);
    const float4 uzn = *(const float4*)(u  + s + dz);
    const float4 uyn = *(const float4*)(u  + s + dy);
    const float  wxp = w [s + 3 + dxp];
    const float  vxp = vv[s + 3 + dxp];

    float wca[4] = {wc.x, wc.y, wc.z, wc.w};
    float vca[4] = {vc.x, vc.y, vc.z, vc.w};
    float wya[4] = {wyn.x, wyn.y, wyn.z, wyn.w};
    float vza[4] = {vzn.x, vzn.y, vzn.z, vzn.w};
    float uca[4] = {uc.x, uc.y, uc.z, uc.w};
    float uza[4] = {uzn.x, uzn.y, uzn.z, uzn.w};
    float uya[4] = {uyn.x, uyn.y, uyn.z, uyn.w};
    float wsh[4] = {wc.y, wc.z, wc.w, wxp};
    float vsh[4] = {vc.y, vc.z, vc.w, vxp};

    float4 o;
    float* oa = &o.x;
#pragma unroll
    for (int j = 0; j < 4; ++j) {
        int x = x0 + j;
        float fdxw = (x < 127) ? (wsh[j] - wca[j]) : (wca[3] - wca[2]);
        float fdxv = (x < 127) ? (vsh[j] - vca[j]) : (vca[3] - vca[2]);
        float fdyw = sy * (wya[j] - wca[j]);
        float fdyu = sy * (uya[j] - uca[j]);
        float fdzv = sz * (vza[j] - vca[j]);
        float fdzu = sz * (uza[j] - uca[j]);
        float cu = fdyw - fdzv;
        float cv = fdzu - fdxw;
        float cw = fdxv - fdyu;
        oa[j] = sqrtf(cu * cu + cv * cv + cw * cw);
    }
    return o;
}

// ---------------------------------------------------------------------------
// Dual-mode fused kernel, one (n, z, y-16-chunk) slab per block.
//   even blocks: stage d rows in LDS             -> y-conv -> x-conv -> P
//   odd  blocks: compute |curl(v)| rows into LDS -> y-conv -> x-conv -> Q
// Parity interleave co-schedules cheap d-blocks with load-heavy curl-blocks.
// LDS 20224 B -> 8 blocks/CU; launch_bounds(256,6) keeps VGPR cap ~85 (>52
// measured in R9 -- no spill) while allowing ~6 blocks/CU residency.
__global__ __launch_bounds__(256, 6)
void yx_curl_dual_kernel(const float* __restrict__ dIn, float* __restrict__ P,
                         const float* __restrict__ v,   float* __restrict__ Q,
                         GaussW gw) {
    __shared__ float in_t[22][128];    // field rows y0-3 .. y0+18 of slice z (11264 B)
    __shared__ float mid[16][140];     // col = x+4; halo cols 0-3 & 132-135 zero (8960 B)

    int bb = blockIdx.x;               // 8192
    bool isCurl = (bb & 1);
    int b  = bb >> 1;                  // 4096
    int yq = b & 7;
    int z  = (b >> 3) & 127;
    int n  = b >> 10;
    int y0 = yq * 16;
    size_t slice = (((size_t)n << 7) | (size_t)z) << 14;
    int tid = threadIdx.x;

    if (!isCurl) {
        for (int j = tid; j < 22 * 32; j += 256) {
            int r  = j >> 5;
            int c4 = (j & 31) << 2;
            int gy = y0 - 3 + r;
            float4 val = (gy >= 0 && gy < 128)
                       ? *(const float4*)(dIn + slice + ((size_t)gy << 7) + c4)
                       : f4zero();
            *(float4*)&in_t[r][c4] = val;
        }
    } else {
        const float* u  = v + (size_t)n * 3 * VOX;
        const float* vv = u + VOX;
        const float* w  = vv + VOX;
        for (int j = tid; j < 22 * 32; j += 256) {
            int r  = j >> 5;
            int c4 = (j & 31) << 2;
            int gy = y0 - 3 + r;
            float4 val = (gy >= 0 && gy < 128)
                       ? curl4_at(u, vv, w, z, gy, c4)
                       : f4zero();
            *(float4*)&in_t[r][c4] = val;
        }
    }
    __syncthreads();

    if (tid < 16) {
        *(float4*)&mid[tid][0]   = f4zero();
        *(float4*)&mid[tid][132] = f4zero();
    }
    // y-conv -> mid
    for (int j = tid; j < 16 * 32; j += 256) {
        int yo = j >> 5;
        int c4 = (j & 31) << 2;
        float4 a = f4zero();
#pragma unroll
        for (int k = 0; k < 7; ++k) {
            float wk = gw.w[k];
            float4 t = *(const float4*)&in_t[yo + k][c4];
            a.x += wk * t.x; a.y += wk * t.y; a.z += wk * t.z; a.w += wk * t.w;
        }
        *(float4*)&mid[yo][c4 + 4] = a;
    }
    __syncthreads();

    // x-conv -> global
    float* out = isCurl ? Q : P;
    for (int j = tid; j < 16 * 32; j += 256) {
        int yo  = j >> 5;
        int x0c = (j & 31) << 2;
        float4 m0 = *(const float4*)&mid[yo][x0c];
        float4 m1 = *(const float4*)&mid[yo][x0c + 4];
        float4 m2 = *(const float4*)&mid[yo][x0c + 8];
        float wdw[12] = {m0.x, m0.y, m0.z, m0.w,
                         m1.x, m1.y, m1.z, m1.w,
                         m2.x, m2.y, m2.z, m2.w};
        float o[4];
#pragma unroll
        for (int j2 = 0; j2 < 4; ++j2) {
            float acc = 0.f;
#pragma unroll
            for (int k = 0; k < 7; ++k) acc += gw.w[k] * wdw[j2 + 1 + k];
            o[j2] = acc;
        }
        *(float4*)(out + slice + ((size_t)(y0 + yo) << 7) + x0c) =
            make_float4(o[0], o[1], o[2], o[3]);
    }
}

// ---------------------------------------------------------------------------
// Render with on-the-fly z-smooth of both fields, DOUBLE-BUFFERED:
// batch b+1's 32 loads are issued before batch b's compute, so the 1-wave/SIMD
// grid overlaps HBM latency with the transmittance/trapezoid math.
#define RBATCH 16
__global__ __launch_bounds__(256, 2)
void render_zs_kernel(const float* __restrict__ P, const float* __restrict__ Q,
                      float* __restrict__ out, GaussW gw) {
    int idx = blockIdx.x * blockDim.x + threadIdx.x;  // NB*HH*WW = 65536
    if (idx >= NB * HH * WW) return;
    int x = idx & 127;
    int y = (idx >> 7) & 127;
    int n = idx >> 14;
    size_t volbase = (size_t)n * VOX + ((size_t)y << 7) + x;

    // carry = pf/qf[j0-3 .. j0+2] entering each batch (pf[j] = P[z=127-j])
    float pc[6], qc[6];
#pragma unroll
    for (int t = 0; t < 3; ++t) { pc[t] = 0.f; qc[t] = 0.f; }
#pragma unroll
    for (int t = 3; t < 6; ++t) {
        int j = t - 3;
        size_t off = volbase + ((size_t)(127 - j) << 14);
        pc[t] = P[off];
        qc[t] = Q[off];
    }

    // prefetch batch 0 body: pf[3..18]
    float nds[RBATCH], nvn[RBATCH];
#pragma unroll
    for (int i = 0; i < RBATCH; ++i) {
        size_t off = volbase + ((size_t)(127 - (3 + i)) << 14);
        nds[i] = P[off];
        nvn[i] = Q[off];
    }

    float xacc = 0.f, acc = 0.f, tp = 0.f, vp = 0.f;
    for (int b = 0; b < 128 / RBATCH; ++b) {
        int j0 = b * RBATCH;
        float pw[RBATCH + 6], qw[RBATCH + 6];
#pragma unroll
        for (int t = 0; t < 6; ++t)      { pw[t] = pc[t];         qw[t] = qc[t]; }
#pragma unroll
        for (int i = 0; i < RBATCH; ++i) { pw[6 + i] = nds[i];    qw[6 + i] = nvn[i]; }

        // issue next batch's loads before computing this batch
        if (b < 7) {
#pragma unroll
            for (int i = 0; i < RBATCH; ++i) {
                int j = j0 + RBATCH + 3 + i;
                if (j <= 127) {
                    size_t off = volbase + ((size_t)(127 - j) << 14);
                    nds[i] = P[off];
                    nvn[i] = Q[off];
                } else {
                    nds[i] = 0.f;
                    nvn[i] = 0.f;
                }
            }
        }

#pragma unroll
        for (int i = 0; i < RBATCH; ++i) {
            float dsf = 0.f, vnf = 0.f;
#pragma unroll
            for (int k = 0; k < 7; ++k) {
                float wk = gw.w[k];
                dsf += wk * pw[i + k];
                vnf += wk * qw[i + k];
            }
            xacc += dsf;
            float xc = 20.f * xacc;
            float tk = (xc + 1.f) * __expf(-xc);
            if (j0 + i == 0) acc = (1.f - tk) * vnf;
            else             acc += (tp - tk) * (vp + vnf) * 0.5f;
            tp = tk; vp = vnf;
        }
#pragma unroll
        for (int t = 0; t < 6; ++t) { pc[t] = pw[RBATCH + t]; qc[t] = qw[RBATCH + t]; }
    }
    out[idx] = fminf(fmaxf(acc, 0.f), 1.f);
}

// ---------------------------------------------------------------------------
extern "C" void kernel_launch(void* const* d_in, const int* in_sizes, int n_in,
                              void* d_out, int out_size, void* d_ws, size_t ws_size,
                              hipStream_t stream) {
    const float* d = (const float*)d_in[0];   // (4,1,128,128,128)
    const float* v = (const float*)d_in[1];   // (4,3,128,128,128)
    float* out = (float*)d_out;               // (4,1,128,128)

    GaussW gw;
    {
        double g[7], s = 0.0;
        for (int i = 0; i < 7; ++i) {
            double t = (i - 3) / 1.6;
            g[i] = exp(-t * t / 2.0);
            s += g[i];
        }
        for (int i = 0; i < 7; ++i) gw.w[i] = (float)(g[i] / s);
    }

    float* ws0 = (float*)d_ws;        // P = yx-smoothed d
    float* ws1 = ws0 + NVOX;          // Q = yx-smoothed |curl|

    const int TB = 256;

    // 1) fused: d yx-smooth (even blocks) + curl-on-the-fly yx-smooth (odd)
    yx_curl_dual_kernel<<<2 * NB * DD * (HH / 16), TB, 0, stream>>>(d, ws0, v, ws1, gw);

    // 2) render with on-the-fly z-smooth of both fields (double-buffered)
    render_zs_kernel<<<(NB * HH * WW) / TB, TB, 0, stream>>>(ws0, ws1, out, gw);
}

// Round 11
// 198.160 us; speedup vs baseline: 1.1239x; 1.1239x over previous
//
#include <hip/hip_runtime.h>
#include <math.h>

#define NB 4
#define DD 128
#define HH 128
#define WW 128
#define VOX (DD*HH*WW)          // 2097152 = 2^21
#define NVOX (NB*VOX)           // 8388608

struct GaussW { float w[7]; };

__device__ __forceinline__ float4 f4zero() { float4 z; z.x = z.y = z.z = z.w = 0.f; return z; }

// ---------------------------------------------------------------------------
// |curl| of one float4 at (z, y, x0). Matches _fdiff (dup-last forward diff).
__device__ __forceinline__ float4 curl4_at(const float* __restrict__ u,
                                           const float* __restrict__ vv,
                                           const float* __restrict__ w,
                                           int z, int y, int x0) {
    int xq = x0 >> 2;
    size_t s = ((size_t)z << 14) | ((size_t)y << 7) | (size_t)x0;
    int dy = (y < 127) ? 128 : -128;
    int dz = (z < 127) ? 16384 : -16384;
    float sy = (y < 127) ? 1.f : -1.f;
    float sz = (z < 127) ? 1.f : -1.f;
    int dxp = (xq < 31) ? 4 : 0;

    const float4 wc  = *(const float4*)(w  + s);
    const float4 wyn = *(const float4*)(w  + s + dy);
    const float4 vc  = *(const float4*)(vv + s);
    const float4 vzn = *(const float4*)(vv + s + dz);
    const float4 uc  = *(const float4*)(u  + s);
    const float4 uzn = *(const float4*)(u  + s + dz);
    const float4 uyn = *(const float4*)(u  + s + dy);
    const float  wxp = w [s + 3 + dxp];
    const float  vxp = vv[s + 3 + dxp];

    float wca[4] = {wc.x, wc.y, wc.z, wc.w};
    float vca[4] = {vc.x, vc.y, vc.z, vc.w};
    float wya[4] = {wyn.x, wyn.y, wyn.z, wyn.w};
    float vza[4] = {vzn.x, vzn.y, vzn.z, vzn.w};
    float uca[4] = {uc.x, uc.y, uc.z, uc.w};
    float uza[4] = {uzn.x, uzn.y, uzn.z, uzn.w};
    float uya[4] = {uyn.x, uyn.y, uyn.z, uyn.w};
    float wsh[4] = {wc.y, wc.z, wc.w, wxp};
    float vsh[4] = {vc.y, vc.z, vc.w, vxp};

    float4 o;
    float* oa = &o.x;
#pragma unroll
    for (int j = 0; j < 4; ++j) {
        int x = x0 + j;
        float fdxw = (x < 127) ? (wsh[j] - wca[j]) : (wca[3] - wca[2]);
        float fdxv = (x < 127) ? (vsh[j] - vca[j]) : (vca[3] - vca[2]);
        float fdyw = sy * (wya[j] - wca[j]);
        float fdyu = sy * (uya[j] - uca[j]);
        float fdzv = sz * (vza[j] - vca[j]);
        float fdzu = sz * (uza[j] - uca[j]);
        float cu = fdyw - fdzv;
        float cv = fdzu - fdxw;
        float cw = fdxv - fdyu;
        oa[j] = sqrtf(cu * cu + cv * cv + cw * cw);
    }
    return o;
}

// ---------------------------------------------------------------------------
// Dual-mode fused kernel, one (n, z, y-quarter=32) slab per block.
//   blocks [0,2048):    stage d rows in LDS             -> y -> x -> P
//   blocks [2048,4096): compute |curl(v)| rows into LDS -> y -> x -> Q
// SINGLE 19.5 KB LDS buffer (in_t reused as mid after a sync): 8 blocks/CU
// by LDS vs R9's 4 at 36 KB. launch_bounds(256,4) keeps VGPR cap 128 so the
// curl staging's 9 loads/float4 stay in flight (R10's (256,6)->32 VGPR
// squeeze serialized them: 70->92 us).
__global__ __launch_bounds__(256, 4)
void yx_curl_dual_kernel(const float* __restrict__ dIn, float* __restrict__ P,
                         const float* __restrict__ v,   float* __restrict__ Q,
                         GaussW gw) {
    __shared__ float in_t[38][128];    // rows y0-3 .. y0+34 (19456 B)

    int bb = blockIdx.x;               // 4096
    bool isCurl = (bb >= 2048);
    int b  = bb & 2047;
    int yq = b & 3;
    int z  = (b >> 2) & 127;
    int n  = b >> 9;
    int y0 = yq * 32;
    size_t slice = (((size_t)n << 7) | (size_t)z) << 14;
    int tid = threadIdx.x;

    if (!isCurl) {
        for (int j = tid; j < 38 * 32; j += 256) {
            int r  = j >> 5;
            int c4 = (j & 31) << 2;
            int gy = y0 - 3 + r;
            float4 val = (gy >= 0 && gy < 128)
                       ? *(const float4*)(dIn + slice + ((size_t)gy << 7) + c4)
                       : f4zero();
            *(float4*)&in_t[r][c4] = val;
        }
    } else {
        const float* u  = v + (size_t)n * 3 * VOX;
        const float* vv = u + VOX;
        const float* w  = vv + VOX;
        for (int j = tid; j < 38 * 32; j += 256) {
            int r  = j >> 5;
            int c4 = (j & 31) << 2;
            int gy = y0 - 3 + r;
            float4 val = (gy >= 0 && gy < 128)
                       ? curl4_at(u, vv, w, z, gy, c4)
                       : f4zero();
            *(float4*)&in_t[r][c4] = val;
        }
    }
    __syncthreads();

    // y-conv into registers (4 float4 per thread covering 32x32 float4 grid)
    float4 rr[4];
#pragma unroll
    for (int t = 0; t < 4; ++t) {
        int j  = tid + t * 256;
        int yo = j >> 5;
        int c4 = (j & 31) << 2;
        float4 a = f4zero();
#pragma unroll
        for (int k = 0; k < 7; ++k) {
            float wk = gw.w[k];
            float4 tv = *(const float4*)&in_t[yo + k][c4];
            a.x += wk * tv.x; a.y += wk * tv.y; a.z += wk * tv.z; a.w += wk * tv.w;
        }
        rr[t] = a;
    }
    __syncthreads();

    // write y-conv results back into in_t rows 0..31 (reuse as mid, no halo)
#pragma unroll
    for (int t = 0; t < 4; ++t) {
        int j  = tid + t * 256;
        int yo = j >> 5;
        int c4 = (j & 31) << 2;
        *(float4*)&in_t[yo][c4] = rr[t];
    }
    __syncthreads();

    // x-conv -> global, zero-pad at x edges via guarded loads
    float* out = isCurl ? Q : P;
#pragma unroll
    for (int t = 0; t < 4; ++t) {
        int j   = tid + t * 256;
        int yo  = j >> 5;
        int x0c = (j & 31) << 2;
        float4 q0 = (x0c > 0)   ? *(const float4*)&in_t[yo][x0c - 4] : f4zero();
        float4 q1 =               *(const float4*)&in_t[yo][x0c];
        float4 q2 = (x0c < 124) ? *(const float4*)&in_t[yo][x0c + 4] : f4zero();
        float wdw[11] = {q0.y, q0.z, q0.w,
                         q1.x, q1.y, q1.z, q1.w,
                         q2.x, q2.y, q2.z, q2.w};
        float o[4];
#pragma unroll
        for (int j2 = 0; j2 < 4; ++j2) {
            float acc = 0.f;
#pragma unroll
            for (int k = 0; k < 7; ++k) acc += gw.w[k] * wdw[j2 + k];
            o[j2] = acc;
        }
        *(float4*)(out + slice + ((size_t)(y0 + yo) << 7) + x0c) =
            make_float4(o[0], o[1], o[2], o[3]);
    }
}

// ---------------------------------------------------------------------------
// Render, 4-way z-chunk parallel. Block = 64 columns x 4 chunks of 32 z
// (flipped coords j = 127-z). Each thread: burst-load 38 P values, z-smooth
// in place, chunk-sum -> LDS scan gives cumsum offset; burst-load 39 Q
// values; boundary (tp,vp) from offset + 7-tap at j0-1; trapezoid partials
// summed in LDS. Replaces the serial 1-block/CU column walk (was ~66 us).
__global__ __launch_bounds__(256, 4)
void render_zs4_kernel(const float* __restrict__ P, const float* __restrict__ Q,
                       float* __restrict__ out, GaussW gw) {
    __shared__ float csum[4][64];
    __shared__ float part[4][64];

    int xl = threadIdx.x & 63;
    int ch = threadIdx.x >> 6;
    int col = blockIdx.x * 64 + xl;       // 1024 blocks * 64 = 65536 columns
    int x = col & 127;
    int y = (col >> 7) & 127;
    int n = col >> 14;
    size_t volbase = ((size_t)n << 21) | ((size_t)y << 7) | (size_t)x;
    int j0 = ch * 32;

    // burst-load pf[j0-3 .. j0+34] (zero outside [0,127])
    float a[38];
#pragma unroll
    for (int t = 0; t < 38; ++t) {
        int j = j0 - 3 + t;
        a[t] = (j >= 0 && j <= 127) ? P[volbase + ((size_t)(127 - j) << 14)] : 0.f;
    }
    // in-place z-smooth: a[i] <- dsf[j0+i] (reads a[i..i+6], writes a[i])
#pragma unroll
    for (int i = 0; i < 32; ++i) {
        float s = 0.f;
#pragma unroll
        for (int k = 0; k < 7; ++k) s += gw.w[k] * a[i + k];
        a[i] = s;
    }
    float S = 0.f;
#pragma unroll
    for (int i = 0; i < 32; ++i) S += a[i];
    csum[ch][xl] = S;

    // burst-load qf[j0-4 .. j0+34] while the barrier drains
    float bq[39];
#pragma unroll
    for (int t = 0; t < 39; ++t) {
        int j = j0 - 4 + t;
        bq[t] = (j >= 0 && j <= 127) ? Q[volbase + ((size_t)(127 - j) << 14)] : 0.f;
    }
    __syncthreads();

    float offset = 0.f;
    if (ch > 0) offset += csum[0][xl];
    if (ch > 1) offset += csum[1][xl];
    if (ch > 2) offset += csum[2][xl];

    float tp = 0.f, vp = 0.f, acc = 0.f, xacc = offset;
    if (ch > 0) {
        float v0 = 0.f;
#pragma unroll
        for (int k = 0; k < 7; ++k) v0 += gw.w[k] * bq[k];   // vnf[j0-1]
        vp = v0;
        float xc = 20.f * offset;
        tp = (xc + 1.f) * __expf(-xc);
    }
#pragma unroll
    for (int i = 0; i < 32; ++i) {
        xacc += a[i];
        float vk = 0.f;
#pragma unroll
        for (int k = 0; k < 7; ++k) vk += gw.w[k] * bq[i + 1 + k];  // vnf[j0+i]
        float xc = 20.f * xacc;
        float tk = (xc + 1.f) * __expf(-xc);
        if (ch == 0 && i == 0) acc = (1.f - tk) * vk;               // front term
        else                   acc += (tp - tk) * (vp + vk) * 0.5f; // trapezoid
        tp = tk; vp = vk;
    }
    part[ch][xl] = acc;
    __syncthreads();

    if (ch == 0) {
        float r = part[0][xl] + part[1][xl] + part[2][xl] + part[3][xl];
        out[col] = fminf(fmaxf(r, 0.f), 1.f);
    }
}

// ---------------------------------------------------------------------------
extern "C" void kernel_launch(void* const* d_in, const int* in_sizes, int n_in,
                              void* d_out, int out_size, void* d_ws, size_t ws_size,
                              hipStream_t stream) {
    const float* d = (const float*)d_in[0];   // (4,1,128,128,128)
    const float* v = (const float*)d_in[1];   // (4,3,128,128,128)
    float* out = (float*)d_out;               // (4,1,128,128)

    GaussW gw;
    {
        double g[7], s = 0.0;
        for (int i = 0; i < 7; ++i) {
            double t = (i - 3) / 1.6;
            g[i] = exp(-t * t / 2.0);
            s += g[i];
        }
        for (int i = 0; i < 7; ++i) gw.w[i] = (float)(g[i] / s);
    }

    float* ws0 = (float*)d_ws;        // P = yx-smoothed d
    float* ws1 = ws0 + NVOX;          // Q = yx-smoothed |curl|

    const int TB = 256;

    // 1) fused: d yx-smooth (blocks 0-2047) + curl-on-the-fly yx-smooth (2048-4095)
    yx_curl_dual_kernel<<<2 * NB * DD * 4, TB, 0, stream>>>(d, ws0, v, ws1, gw);

    // 2) render: 4-way z-chunk parallel with LDS scan + on-the-fly z-smooth
    render_zs4_kernel<<<(NB * HH * WW) / 64, TB, 0, stream>>>(ws0, ws1, out, gw);
}

// Round 12
// 191.336 us; speedup vs baseline: 1.1639x; 1.0357x over previous
//
#include <hip/hip_runtime.h>
#include <math.h>

#define NB 4
#define DD 128
#define HH 128
#define WW 128
#define VOX (DD*HH*WW)          // 2097152 = 2^21
#define NVOX (NB*VOX)           // 8388608

struct GaussW { float w[7]; };
struct CurlIn { float4 wc, wyn, vc, vzn, uc, uzn, uyn; float wxp, vxp; };

__device__ __forceinline__ float4 f4zero() { float4 z; z.x = z.y = z.z = z.w = 0.f; return z; }

// ---------------------------------------------------------------------------
// Split curl into LOAD (issueable in bursts) and MATH phases so the source
// can force all tasks' loads into flight before any consumer (R11 showed the
// compiler allocates 32 VGPR and serializes if loads+ds_write share a loop).
__device__ __forceinline__ CurlIn curl4_load(const float* __restrict__ u,
                                             const float* __restrict__ vv,
                                             const float* __restrict__ w,
                                             int z, int y, int x0) {
    int xq = x0 >> 2;
    size_t s = ((size_t)z << 14) | ((size_t)y << 7) | (size_t)x0;
    int dy = (y < 127) ? 128 : -128;
    int dz = (z < 127) ? 16384 : -16384;
    int dxp = (xq < 31) ? 4 : 0;
    CurlIn ci;
    ci.wc  = *(const float4*)(w  + s);
    ci.wyn = *(const float4*)(w  + s + dy);
    ci.vc  = *(const float4*)(vv + s);
    ci.vzn = *(const float4*)(vv + s + dz);
    ci.uc  = *(const float4*)(u  + s);
    ci.uzn = *(const float4*)(u  + s + dz);
    ci.uyn = *(const float4*)(u  + s + dy);
    ci.wxp = w [s + 3 + dxp];
    ci.vxp = vv[s + 3 + dxp];
    return ci;
}

__device__ __forceinline__ float4 curl4_math(const CurlIn& ci, int z, int y, int x0) {
    float sy = (y < 127) ? 1.f : -1.f;
    float sz = (z < 127) ? 1.f : -1.f;
    float wca[4] = {ci.wc.x, ci.wc.y, ci.wc.z, ci.wc.w};
    float vca[4] = {ci.vc.x, ci.vc.y, ci.vc.z, ci.vc.w};
    float wya[4] = {ci.wyn.x, ci.wyn.y, ci.wyn.z, ci.wyn.w};
    float vza[4] = {ci.vzn.x, ci.vzn.y, ci.vzn.z, ci.vzn.w};
    float uca[4] = {ci.uc.x, ci.uc.y, ci.uc.z, ci.uc.w};
    float uza[4] = {ci.uzn.x, ci.uzn.y, ci.uzn.z, ci.uzn.w};
    float uya[4] = {ci.uyn.x, ci.uyn.y, ci.uyn.z, ci.uyn.w};
    float wsh[4] = {ci.wc.y, ci.wc.z, ci.wc.w, ci.wxp};
    float vsh[4] = {ci.vc.y, ci.vc.z, ci.vc.w, ci.vxp};

    float4 o;
    float* oa = &o.x;
#pragma unroll
    for (int j = 0; j < 4; ++j) {
        int x = x0 + j;
        float fdxw = (x < 127) ? (wsh[j] - wca[j]) : (wca[3] - wca[2]);
        float fdxv = (x < 127) ? (vsh[j] - vca[j]) : (vca[3] - vca[2]);
        float fdyw = sy * (wya[j] - wca[j]);
        float fdyu = sy * (uya[j] - uca[j]);
        float fdzv = sz * (vza[j] - vca[j]);
        float fdzu = sz * (uza[j] - uca[j]);
        float cu = fdyw - fdzv;
        float cv = fdzu - fdxw;
        float cw = fdxv - fdyu;
        oa[j] = sqrtf(cu * cu + cv * cv + cw * cw);
    }
    return o;
}

// ---------------------------------------------------------------------------
// Dual-mode fused kernel, 512 threads, one (n, z, y-quarter=32) slab per block.
//   blocks [0,2048):    stage d rows in LDS             -> y -> x -> P
//   blocks [2048,4096): compute |curl(v)| rows into LDS -> y -> x -> Q
// Staging is HOISTED: all 3 tasks' inputs (27 float4 + 6 scalar for curl)
// load into registers before any math/ds_write -> 1 latency round, not 5.
// LDS 19456 B; launch_bounds(512,2) -> VGPR cap 256 (want ~100-150 live).
__global__ __launch_bounds__(512, 2)
void yx_curl_dual_kernel(const float* __restrict__ dIn, float* __restrict__ P,
                         const float* __restrict__ v,   float* __restrict__ Q,
                         GaussW gw) {
    __shared__ float in_t[38][128];    // rows y0-3 .. y0+34 (19456 B)

    const int NT = 512;
    int bb = blockIdx.x;               // 4096
    bool isCurl = (bb >= 2048);
    int b  = bb & 2047;
    int yq = b & 3;
    int z  = (b >> 2) & 127;
    int n  = b >> 9;
    int y0 = yq * 32;
    size_t slice = (((size_t)n << 7) | (size_t)z) << 14;
    int tid = threadIdx.x;

    if (!isCurl) {
        float4 Ld[3];
#pragma unroll
        for (int t = 0; t < 3; ++t) {          // phase 1: all loads
            int j  = tid + t * NT;
            int r  = j >> 5;
            int c4 = (j & 31) << 2;
            int gy = y0 - 3 + r;
            Ld[t] = (j < 1216 && gy >= 0 && gy < 128)
                  ? *(const float4*)(dIn + slice + ((size_t)gy << 7) + c4)
                  : f4zero();
        }
#pragma unroll
        for (int t = 0; t < 3; ++t) {          // phase 2: LDS writes
            int j = tid + t * NT;
            if (j < 1216) *(float4*)&in_t[j >> 5][(j & 31) << 2] = Ld[t];
        }
    } else {
        const float* u  = v + (size_t)n * 3 * VOX;
        const float* vv = u + VOX;
        const float* w  = vv + VOX;
        CurlIn ci[3];
        bool inb[3];
#pragma unroll
        for (int t = 0; t < 3; ++t) {          // phase 1: burst-issue all loads
            int j  = tid + t * NT;
            int r  = j >> 5;
            int c4 = (j & 31) << 2;
            int gy = y0 - 3 + r;
            inb[t] = (j < 1216 && gy >= 0 && gy < 128);
            if (inb[t]) ci[t] = curl4_load(u, vv, w, z, gy, c4);
        }
#pragma unroll
        for (int t = 0; t < 3; ++t) {          // phase 2: math + LDS writes
            int j  = tid + t * NT;
            if (j < 1216) {
                int r  = j >> 5;
                int c4 = (j & 31) << 2;
                int gy = y0 - 3 + r;
                float4 val = inb[t] ? curl4_math(ci[t], z, gy, c4) : f4zero();
                *(float4*)&in_t[r][c4] = val;
            }
        }
    }
    __syncthreads();

    // y-conv into registers (2 float4 per thread covering the 32x32 float4 grid)
    float4 rr[2];
#pragma unroll
    for (int t = 0; t < 2; ++t) {
        int j  = tid + t * NT;
        int yo = j >> 5;
        int c4 = (j & 31) << 2;
        float4 a = f4zero();
#pragma unroll
        for (int k = 0; k < 7; ++k) {
            float wk = gw.w[k];
            float4 tv = *(const float4*)&in_t[yo + k][c4];
            a.x += wk * tv.x; a.y += wk * tv.y; a.z += wk * tv.z; a.w += wk * tv.w;
        }
        rr[t] = a;
    }
    __syncthreads();

    // write y-conv results back into in_t rows 0..31 (reuse as mid)
#pragma unroll
    for (int t = 0; t < 2; ++t) {
        int j  = tid + t * NT;
        *(float4*)&in_t[j >> 5][(j & 31) << 2] = rr[t];
    }
    __syncthreads();

    // x-conv -> global, zero-pad at x edges via guarded loads
    float* out = isCurl ? Q : P;
#pragma unroll
    for (int t = 0; t < 2; ++t) {
        int j   = tid + t * NT;
        int yo  = j >> 5;
        int x0c = (j & 31) << 2;
        float4 q0 = (x0c > 0)   ? *(const float4*)&in_t[yo][x0c - 4] : f4zero();
        float4 q1 =               *(const float4*)&in_t[yo][x0c];
        float4 q2 = (x0c < 124) ? *(const float4*)&in_t[yo][x0c + 4] : f4zero();
        float wdw[11] = {q0.y, q0.z, q0.w,
                         q1.x, q1.y, q1.z, q1.w,
                         q2.x, q2.y, q2.z, q2.w};
        float o[4];
#pragma unroll
        for (int j2 = 0; j2 < 4; ++j2) {
            float acc = 0.f;
#pragma unroll
            for (int k = 0; k < 7; ++k) acc += gw.w[k] * wdw[j2 + k];
            o[j2] = acc;
        }
        *(float4*)(out + slice + ((size_t)(y0 + yo) << 7) + x0c) =
            make_float4(o[0], o[1], o[2], o[3]);
    }
}

// ---------------------------------------------------------------------------
// Render, 4-way z-chunk parallel (unchanged from R11).
__global__ __launch_bounds__(256, 4)
void render_zs4_kernel(const float* __restrict__ P, const float* __restrict__ Q,
                       float* __restrict__ out, GaussW gw) {
    __shared__ float csum[4][64];
    __shared__ float part[4][64];

    int xl = threadIdx.x & 63;
    int ch = threadIdx.x >> 6;
    int col = blockIdx.x * 64 + xl;       // 1024 blocks * 64 = 65536 columns
    int x = col & 127;
    int y = (col >> 7) & 127;
    int n = col >> 14;
    size_t volbase = ((size_t)n << 21) | ((size_t)y << 7) | (size_t)x;
    int j0 = ch * 32;

    float a[38];
#pragma unroll
    for (int t = 0; t < 38; ++t) {
        int j = j0 - 3 + t;
        a[t] = (j >= 0 && j <= 127) ? P[volbase + ((size_t)(127 - j) << 14)] : 0.f;
    }
#pragma unroll
    for (int i = 0; i < 32; ++i) {
        float s = 0.f;
#pragma unroll
        for (int k = 0; k < 7; ++k) s += gw.w[k] * a[i + k];
        a[i] = s;
    }
    float S = 0.f;
#pragma unroll
    for (int i = 0; i < 32; ++i) S += a[i];
    csum[ch][xl] = S;

    float bq[39];
#pragma unroll
    for (int t = 0; t < 39; ++t) {
        int j = j0 - 4 + t;
        bq[t] = (j >= 0 && j <= 127) ? Q[volbase + ((size_t)(127 - j) << 14)] : 0.f;
    }
    __syncthreads();

    float offset = 0.f;
    if (ch > 0) offset += csum[0][xl];
    if (ch > 1) offset += csum[1][xl];
    if (ch > 2) offset += csum[2][xl];

    float tp = 0.f, vp = 0.f, acc = 0.f, xacc = offset;
    if (ch > 0) {
        float v0 = 0.f;
#pragma unroll
        for (int k = 0; k < 7; ++k) v0 += gw.w[k] * bq[k];   // vnf[j0-1]
        vp = v0;
        float xc = 20.f * offset;
        tp = (xc + 1.f) * __expf(-xc);
    }
#pragma unroll
    for (int i = 0; i < 32; ++i) {
        xacc += a[i];
        float vk = 0.f;
#pragma unroll
        for (int k = 0; k < 7; ++k) vk += gw.w[k] * bq[i + 1 + k];  // vnf[j0+i]
        float xc = 20.f * xacc;
        float tk = (xc + 1.f) * __expf(-xc);
        if (ch == 0 && i == 0) acc = (1.f - tk) * vk;
        else                   acc += (tp - tk) * (vp + vk) * 0.5f;
        tp = tk; vp = vk;
    }
    part[ch][xl] = acc;
    __syncthreads();

    if (ch == 0) {
        float r = part[0][xl] + part[1][xl] + part[2][xl] + part[3][xl];
        out[col] = fminf(fmaxf(r, 0.f), 1.f);
    }
}

// ---------------------------------------------------------------------------
extern "C" void kernel_launch(void* const* d_in, const int* in_sizes, int n_in,
                              void* d_out, int out_size, void* d_ws, size_t ws_size,
                              hipStream_t stream) {
    const float* d = (const float*)d_in[0];   // (4,1,128,128,128)
    const float* v = (const float*)d_in[1];   // (4,3,128,128,128)
    float* out = (float*)d_out;               // (4,1,128,128)

    GaussW gw;
    {
        double g[7], s = 0.0;
        for (int i = 0; i < 7; ++i) {
            double t = (i - 3) / 1.6;
            g[i] = exp(-t * t / 2.0);
            s += g[i];
        }
        for (int i = 0; i < 7; ++i) gw.w[i] = (float)(g[i] / s);
    }

    float* ws0 = (float*)d_ws;        // P = yx-smoothed d
    float* ws1 = ws0 + NVOX;          // Q = yx-smoothed |curl|

    // 1) fused: d yx-smooth (blocks 0-2047) + curl-on-the-fly yx-smooth (2048-4095)
    yx_curl_dual_kernel<<<2 * NB * DD * 4, 512, 0, stream>>>(d, ws0, v, ws1, gw);

    // 2) render: 4-way z-chunk parallel with LDS scan + on-the-fly z-smooth
    render_zs4_kernel<<<(NB * HH * WW) / 64, 256, 0, stream>>>(ws0, ws1, out, gw);
}